// Round 13
// baseline (70.725 us; speedup 1.0000x reference)
//
#include <hip/hip_runtime.h>
#include <math.h>
#include <stdint.h>

#define KK 5
#define PADK 2
#define C_IN 8
#define O_OUT 8
#define HH 512
#define WW 512
#define TH 8
#define TW 128
#define CH 4                      // channels per staged half
#define LROWS 12                  // TH + 4
#define LCOLS 136                 // TW + 4 halo, padded (f32 cols)
#define WCH 56                    // dwords per (c,og) weight chunk (50 used, 16B-aligned)
#define NW (O_OUT * C_IN * KK * KK)   // 1600
#define XHALF (CH * LROWS * (LCOLS / 2))   // float2 slots per half = 3264

// Full-rate VOP3 3-input max.
static __device__ __forceinline__ float max3f(float a, float b, float c) {
    float d;
    asm("v_max3_f32 %0, %1, %2, %3" : "=v"(d) : "v"(a), "v"(b), "v"(c));
    return d;
}

__global__ __launch_bounds__(512, 4)
void dil_kernel(const float* __restrict__ x,
                const float* __restrict__ wf,
                float* __restrict__ out) {
    __shared__ __align__(16) float xlds[CH][LROWS][LCOLS];      // 26,112 B
    __shared__ __align__(16) float wlds[C_IN * 4 * WCH];        //  7,168 B

    const int tid = threadIdx.x;
    const int w0 = blockIdx.x * TW;
    const int h0 = blockIdx.y * TH;
    const int n  = blockIdx.z;
    const float* xn = x + (size_t)n * (C_IN * HH * WW);

    // wave -> (o-pair og, row-quad rq); lane -> 2-pixel column strip
    const int l   = tid & 63;
    const int wid = tid >> 6;
    const int og  = wid & 3;
    const int rq  = wid >> 2;          // 0..1
    const int rbase = rq * 4;

    float acc[2][4][2];
    #pragma unroll
    for (int a = 0; a < 2; ++a)
        #pragma unroll
        for (int j = 0; j < 4; ++j) {
            acc[a][j][0] = -INFINITY;
            acc[a][j][1] = -INFINITY;
        }

    for (int h = 0; h < 2; ++h) {
        if (h) __syncthreads();        // all waves done with xlds half 0

        // ---- stage x half (4 channels), zero halo == reference zero pad ----
        for (int idx = tid; idx < XHALF; idx += 512) {
            int cc  = idx / (LROWS * (LCOLS / 2));
            int rem = idx - cc * (LROWS * (LCOLS / 2));
            int r   = rem / (LCOLS / 2);
            int jp  = rem - r * (LCOLS / 2);
            int gh = h0 - PADK + r;
            int gw = w0 - PADK + 2 * jp;
            float v0 = 0.f, v1 = 0.f;
            if ((unsigned)gh < (unsigned)HH) {
                const float* row = xn + ((size_t)(h * CH + cc) * HH + gh) * WW;
                if ((unsigned)gw < (unsigned)WW) v0 = row[gw];
                if ((unsigned)(gw + 1) < (unsigned)WW) v1 = row[gw + 1];
            }
            *(float2*)&xlds[cc][r][2 * jp] = make_float2(v0, v1);
        }
        // ---- stage weights once: layout [c][og] -> 50 contiguous dwords
        //      (dy*10 + o2*5 + dx), chunk padded to 56 for 16B alignment ----
        if (h == 0) {
            for (int t = tid; t < NW; t += 512) {
                // t enumerates (o,c,dy,dx) row-major == wf's own layout
                int dx = t % KK;  int q = t / KK;
                int dy = q % KK;  q /= KK;
                int c  = q % C_IN;
                int o  = q / C_IN;
                int g  = o >> 1, o2 = o & 1;
                wlds[(c * 4 + g) * WCH + dy * 10 + o2 * KK + dx] = wf[t];
            }
        }
        __syncthreads();

        for (int cc = 0; cc < CH; ++cc) {
            const int c = h * CH + cc;

            // ---- batch ALL x rows for this c into registers (24x b64) ----
            float U[8][6];
            #pragma unroll
            for (int r = 0; r < 8; ++r) {
                const float* lr = &xlds[cc][rbase + r][2 * l];
                float2 a = *(const float2*)(lr);
                float2 b = *(const float2*)(lr + 2);
                float2 d = *(const float2*)(lr + 4);
                U[r][0] = a.x; U[r][1] = a.y;
                U[r][2] = b.x; U[r][3] = b.y;
                U[r][4] = d.x; U[r][5] = d.y;
            }
            // ---- batch ALL weights for (c, og) across 5 dy (13 reads) ----
            float W[50];
            {
                const float* wc = &wlds[(c * 4 + og) * WCH];
                #pragma unroll
                for (int k = 0; k < 12; ++k) {
                    float4 v = *(const float4*)(wc + 4 * k);
                    W[4 * k + 0] = v.x; W[4 * k + 1] = v.y;
                    W[4 * k + 2] = v.z; W[4 * k + 3] = v.w;
                }
                float2 v = *(const float2*)(wc + 48);
                W[48] = v.x; W[49] = v.y;
            }

            // ---- pure VALU: 1280 instrs, zero memory ops ----
            #pragma unroll
            for (int dy = 0; dy < KK; ++dy) {
                #pragma unroll
                for (int j = 0; j < 4; ++j) {
                    const float u0 = U[dy + j][0], u1 = U[dy + j][1],
                                u2 = U[dy + j][2], u3 = U[dy + j][3],
                                u4 = U[dy + j][4], u5 = U[dy + j][5];
                    #pragma unroll
                    for (int o2 = 0; o2 < 2; ++o2) {
                        const int wb = dy * 10 + o2 * KK;
                        // pixel 0: window u0..u4
                        float t0 = u0 + W[wb + 0], t1 = u1 + W[wb + 1],
                              t2 = u2 + W[wb + 2], t3 = u3 + W[wb + 3],
                              t4 = u4 + W[wb + 4];
                        acc[o2][j][0] = max3f(acc[o2][j][0],
                                              max3f(t0, t1, t2),
                                              fmaxf(t3, t4));
                        // pixel 1: window u1..u5
                        float s0 = u1 + W[wb + 0], s1 = u2 + W[wb + 1],
                              s2 = u3 + W[wb + 2], s3 = u4 + W[wb + 3],
                              s4 = u5 + W[wb + 4];
                        acc[o2][j][1] = max3f(acc[o2][j][1],
                                              max3f(s0, s1, s2),
                                              fmaxf(s3, s4));
                    }
                }
            }
        }
    }

    // ---- store: 2 consecutive pixels -> one float2, coalesced ----
    float* onp = out + (size_t)n * (O_OUT * HH * WW);
    const int hB = h0 + rbase;
    const int wcol = w0 + 2 * l;
    #pragma unroll
    for (int o2 = 0; o2 < 2; ++o2) {
        const int o = og * 2 + o2;
        #pragma unroll
        for (int j = 0; j < 4; ++j) {
            float2 rr = make_float2(acc[o2][j][0], acc[o2][j][1]);
            *(float2*)(&onp[((size_t)o * HH + hB + j) * WW + wcol]) = rr;
        }
    }
}

extern "C" void kernel_launch(void* const* d_in, const int* in_sizes, int n_in,
                              void* d_out, int out_size, void* d_ws, size_t ws_size,
                              hipStream_t stream) {
    const float* x   = (const float*)d_in[0];
    const float* wgt = (const float*)d_in[1];
    float* out = (float*)d_out;

    dim3 grid(WW / TW, HH / TH, 4);   // (4, 64, 4) = 1024 blocks x 512 thr
    dim3 block(512);
    dil_kernel<<<grid, block, 0, stream>>>(x, wgt, out);
}